// Round 21
// baseline (815.910 us; speedup 1.0000x reference)
//
#include <hip/hip_runtime.h>
#include <hip/hip_bf16.h>
#include <hip/hip_cooperative_groups.h>

namespace cg = cooperative_groups;

typedef __attribute__((ext_vector_type(8))) short short8;
typedef __attribute__((ext_vector_type(4))) float f32x4;

#define DEV __device__ __forceinline__

// LDS-only barrier: drains LDS ops, leaves global loads (vmcnt) in flight.
#define BARRIER() do { asm volatile("s_waitcnt lgkmcnt(0)" ::: "memory"); \
                       __builtin_amdgcn_s_barrier(); \
                       __builtin_amdgcn_sched_barrier(0); } while (0)

DEV unsigned short f2bf(float f) {
    unsigned u = __float_as_uint(f);
    u += 0x7FFFu + ((u >> 16) & 1u);
    return (unsigned short)(u >> 16);
}
DEV float bf2f(unsigned short h) { return __uint_as_float(((unsigned)h) << 16); }
DEV unsigned pk2(float lo, float hi) {
    float2 f; f.x = lo; f.y = hi;
    __hip_bfloat162 h = __float22bfloat162_rn(f);
    unsigned r; __builtin_memcpy(&r, &h, 4);
    return r;
}
union S8 { short8 s; unsigned u[4]; };

// ---------------------------------------------------------------------------
// bf16 MFMA GEMM: 64-edge x 192-out tile, 512 threads (8 waves).
// Wave w: col-group c=w&3 (col-tiles [3c,3c+3)), row half rh=w>>2.
// W staged once per block DIRECTLY FROM f32 inputs (inline cvt; no wconv
// kernel, no wbf buffer) -> W fragments hoisted to registers; then
// double-buffered As (2 x 24.6 KB in the same 73.7 KB region) -> ONE
// lgkm barrier per tile. Epilogue = bias + direct packed er store.
//   er[e][0:192] = x_r[e] @ [W0;W1;W2]^T + b   (bf16)
// ---------------------------------------------------------------------------
__global__ __launch_bounds__(512, 2) void gemm_k(
    const float* __restrict__ xr,
    const float* __restrict__ W0, const float* __restrict__ W1, const float* __restrict__ W2,
    const float* __restrict__ b0, const float* __restrict__ b1, const float* __restrict__ b2,
    unsigned short* __restrict__ er,
    int E, int ntiles, int K)
{
    __shared__ __align__(16) unsigned short ShBuf[192 * 192];  // 73.7 KB, overlaid
    unsigned short* Ws = ShBuf;                      // phase 1
    const int t = threadIdx.x;
    const int w = t >> 6, l = t & 63, l15 = l & 15, lg = l >> 4;
    const int cgrp = w & 3, rh = w >> 2;       // col-group, row-half
    const int srow = t >> 3, sq = t & 7;       // staging: 64 rows x 8 thr/row x 24 f32

    // ---- stage W into LDS once, f32 -> bf16 inline: 4608 chunks of 16B ----
#pragma unroll
    for (int j = 0; j < 9; ++j) {
        const int c = j * 512 + t;
        const int gc = c / 24, pos = c - gc * 24;
        const int m = gc >> 6, row = gc & 63;
        const float* Wm = (m == 0) ? W0 : ((m == 1) ? W1 : W2);
        const float4 u0 = *(const float4*)(Wm + row * 192 + pos * 8);
        const float4 u1 = *(const float4*)(Wm + row * 192 + pos * 8 + 4);
        S8 o;
        o.u[0] = pk2(u0.x, u0.y); o.u[1] = pk2(u0.z, u0.w);
        o.u[2] = pk2(u1.x, u1.y); o.u[3] = pk2(u1.z, u1.w);
        const unsigned byte = (unsigned)(gc * 384 + pos * 16);
        *(short8*)((char*)Ws + (byte ^ ((gc & 7) << 4))) = o.s;
    }

    const int G = gridDim.x;
    float4 nv[6];
    // prologue: prefetch tile 0's A slice (in flight during W staging/hoist)
    if (blockIdx.x < ntiles) {
        const long e = (long)blockIdx.x * 64 + srow;
        const bool ok = e < E;
        const float* sp = xr + e * (long)K + sq * 24;
#pragma unroll
        for (int r = 0; r < 6; ++r)
            nv[r] = ok ? *(const float4*)(sp + r * 4) : make_float4(0.f, 0.f, 0.f, 0.f);
    }

    BARRIER();  // Ws visible
    // ---- hoist W fragments to registers (LDS region will be overwritten) ----
    short8 bfr[3][6];
#pragma unroll
    for (int i = 0; i < 3; ++i) {
        const int gc = (cgrp * 3 + i) * 16 + l15;
#pragma unroll
        for (int ks = 0; ks < 6; ++ks) {
            const unsigned byte = (unsigned)(gc * 384 + ks * 64 + lg * 16);
            bfr[i][ks] = *(const short8*)((const char*)Ws + (byte ^ ((gc & 7) << 4)));
        }
    }
    BARRIER();  // all bfr reads done -> region reusable for As buffers

    int p = 0;
    for (int tile = blockIdx.x; tile < ntiles; tile += G, p ^= 1) {
        const long e0 = (long)tile * 64;
        char* Ab = (char*)(ShBuf + p * 64 * 192);
        // ---- convert prefetched regs -> bf16 -> swizzled LDS (buf p) ----
        {
            const unsigned swz = (unsigned)((srow & 7) << 4);
            S8 o0, o1, o2;
            o0.u[0] = pk2(nv[0].x, nv[0].y); o0.u[1] = pk2(nv[0].z, nv[0].w);
            o0.u[2] = pk2(nv[1].x, nv[1].y); o0.u[3] = pk2(nv[1].z, nv[1].w);
            o1.u[0] = pk2(nv[2].x, nv[2].y); o1.u[1] = pk2(nv[2].z, nv[2].w);
            o1.u[2] = pk2(nv[3].x, nv[3].y); o1.u[3] = pk2(nv[3].z, nv[3].w);
            o2.u[0] = pk2(nv[4].x, nv[4].y); o2.u[1] = pk2(nv[4].z, nv[4].w);
            o2.u[2] = pk2(nv[5].x, nv[5].y); o2.u[3] = pk2(nv[5].z, nv[5].w);
            const unsigned byte0 = (unsigned)(srow * 384 + sq * 48);
            *(short8*)(Ab + ((byte0 +  0) ^ swz)) = o0.s;
            *(short8*)(Ab + ((byte0 + 16) ^ swz)) = o1.s;
            *(short8*)(Ab + ((byte0 + 32) ^ swz)) = o2.s;
        }
        // ---- issue next tile's loads (stay in flight through MFMA) ----
        {
            const int nxt = tile + G;
            if (nxt < ntiles) {
                const long e = (long)nxt * 64 + srow;
                const bool ok = e < E;
                const float* sp = xr + e * (long)K + sq * 24;
#pragma unroll
                for (int r = 0; r < 6; ++r)
                    nv[r] = ok ? *(const float4*)(sp + r * 4)
                               : make_float4(0.f, 0.f, 0.f, 0.f);
            }
        }
        BARRIER();  // buf p staging visible (single barrier per tile)
        // ---- MFMA (swapped: D col=edge, row=feature); W from registers ----
        f32x4 acc[2][3];
#pragma unroll
        for (int rt = 0; rt < 2; ++rt)
#pragma unroll
            for (int i = 0; i < 3; ++i) acc[rt][i] = (f32x4)(0.f);
#pragma unroll
        for (int ks = 0; ks < 6; ++ks) {
            short8 af[2];
#pragma unroll
            for (int rt = 0; rt < 2; ++rt) {
                const int row = rh * 32 + rt * 16 + l15;
                const unsigned byte = (unsigned)(row * 384 + ks * 64 + lg * 16);
                af[rt] = *(const short8*)((const char*)Ab + (byte ^ ((row & 7) << 4)));
            }
#pragma unroll
            for (int i = 0; i < 3; ++i)
#pragma unroll
                for (int rt = 0; rt < 2; ++rt)
                    acc[rt][i] = __builtin_amdgcn_mfma_f32_16x16x32_bf16(bfr[i][ks], af[rt], acc[rt][i], 0, 0, 0);
        }
        // ---- epilogue: bias + direct packed er store (no LDS) ----
#pragma unroll
        for (int i = 0; i < 3; ++i) {
            const int ct = cgrp * 3 + i, m = ct >> 2;
            const int cb_ = ((ct & 3) << 4) + (lg << 2);
            const float* bp = (m == 0) ? b0 : ((m == 1) ? b1 : b2);
            const float4 bb = *(const float4*)(bp + cb_);
            const int fb = ct * 16 + (lg << 2);
#pragma unroll
            for (int rt = 0; rt < 2; ++rt) {
                const int edge = rh * 32 + rt * 16 + l15;
                const long ee = e0 + edge;
                if (ee < E) {
                    uint2 pkv;
                    pkv.x = pk2(acc[rt][i][0] + bb.x, acc[rt][i][1] + bb.y);
                    pkv.y = pk2(acc[rt][i][2] + bb.z, acc[rt][i][3] + bb.w);
                    *(uint2*)(er + (size_t)ee * 192 + fb) = pkv;
                }
            }
        }
    }
}

// ---------------------------------------------------------------------------
// Cooperative single-kernel CSR build over 2N segments (h at [0,N), t at
// [N,2N)). Phases separated by grid.sync(); math identical to the previous
// count2/scan1/scan2/off/fill2 kernels.
// ---------------------------------------------------------------------------
__global__ __launch_bounds__(256, 4) void csr_coop_k(
    const int* __restrict__ h, const int* __restrict__ tt,
    int* __restrict__ deg, int* __restrict__ incl, int* __restrict__ bsum,
    int* __restrict__ off, int* __restrict__ cur, int* __restrict__ elist,
    int E, int N)
{
    cg::grid_group grid = cg::this_grid();
    __shared__ int buf[256];
    __shared__ int wsum[4];
    const int M = 2 * N;
    const int gsz = gridDim.x * 256;
    const int gtid = blockIdx.x * 256 + threadIdx.x;
    const int tid = threadIdx.x;
    const int nch = (M + 255) / 256;

    // phase 0: zero deg
    for (int i = gtid; i < M; i += gsz) deg[i] = 0;
    grid.sync();
    // phase 1: count
    for (int e = gtid; e < E; e += gsz) {
        atomicAdd(&deg[h[e]], 1);
        atomicAdd(&deg[N + tt[e]], 1);
    }
    grid.sync();
    // phase 2: per-chunk inclusive scan (chunk = 256 elements)
    for (int c = blockIdx.x; c < nch; c += gridDim.x) {
        const int i = c * 256 + tid;
        buf[tid] = (i < M) ? deg[i] : 0;
        __syncthreads();
        for (int d = 1; d < 256; d <<= 1) {
            int v = (tid >= d) ? buf[tid - d] : 0;
            __syncthreads();
            buf[tid] += v;
            __syncthreads();
        }
        if (i < M) incl[i] = buf[tid];
        if (tid == 255) bsum[c] = buf[255];
        __syncthreads();
    }
    grid.sync();
    // phase 3: block 0 scans bsum inclusive (wave-shuffle)
    if (blockIdx.x == 0) {
        const int l = tid & 63, wv = tid >> 6;
        int base = 0;
        for (int start = 0; start < nch; start += 1024) {
            const int i0 = start + tid * 4;
            int v0 = 0, v1 = 0, v2 = 0, v3 = 0;
            if (i0 < nch)     v0 = bsum[i0];
            if (i0 + 1 < nch) v1 = bsum[i0 + 1];
            if (i0 + 2 < nch) v2 = bsum[i0 + 2];
            if (i0 + 3 < nch) v3 = bsum[i0 + 3];
            const int tsum = v0 + v1 + v2 + v3;
            int sc = tsum;
#pragma unroll
            for (int d = 1; d < 64; d <<= 1) {
                const int o = __shfl_up(sc, d);
                if (l >= d) sc += o;
            }
            if (l == 63) wsum[wv] = sc;
            __syncthreads();
            int woff = base;
            for (int q = 0; q < wv; ++q) woff += wsum[q];
            int run = woff + sc - tsum;
            run += v0; if (i0 < nch)     bsum[i0] = run;
            run += v1; if (i0 + 1 < nch) bsum[i0 + 1] = run;
            run += v2; if (i0 + 2 < nch) bsum[i0 + 2] = run;
            run += v3; if (i0 + 3 < nch) bsum[i0 + 3] = run;
            base += wsum[0] + wsum[1] + wsum[2] + wsum[3];
            __syncthreads();
        }
    }
    grid.sync();
    // phase 4: off / cur
    for (int i = gtid; i < M; i += gsz) {
        const int c = i >> 8;
        const int prev = (c > 0) ? bsum[c - 1] : 0;
        const int o = prev + incl[i] - deg[i];
        off[i] = o;
        cur[i] = o;
    }
    if (gtid == 0) off[M] = 2 * E;
    grid.sync();
    // phase 5: fill
    for (int e = gtid; e < E; e += gsz) {
        const int p = atomicAdd(&cur[h[e]], 1);
        elist[p] = e;
        const int p2 = atomicAdd(&cur[N + tt[e]], 1);
        elist[p2] = e;
    }
}

// ---------------------------------------------------------------------------
// Fully fused 3-block GAT (round-20, unchanged): wave per node, x in
// registers across blocks; ed computed in-register; fast path for deg<=8.
// ---------------------------------------------------------------------------
__global__ __launch_bounds__(256, 6) void gat3_k(
    const int* __restrict__ off, const int* __restrict__ elist,
    const unsigned short* __restrict__ er,
    const float* __restrict__ xe, float* __restrict__ out,
    const float* __restrict__ an0, const float* __restrict__ an1,
    const float* __restrict__ an2,
    const float* __restrict__ ar0, const float* __restrict__ ar1,
    const float* __restrict__ ar2, int N)
{
    __shared__ float sm[4][8][64];
    const int wv = threadIdx.x >> 6;
    const int node = blockIdx.x * 4 + wv;
    if (node >= N) return;
    const int l = threadIdx.x & 63;
    const int g = l >> 3, q = l & 7;

    const int h0 = off[node], h1 = off[node + 1];
    const int t0 = off[N + node], t1 = off[N + node + 1];
    float x = xe[(size_t)node * 64 + l];

    if ((h1 - h0) <= 8 && (t1 - t0) <= 8) {
        const bool vh = g < (h1 - h0), vt = g < (t1 - t0);
        const int eh = vh ? elist[h0 + g] : 0;
        const int et = vt ? elist[t0 + g] : 0;
        short8 w0, w1, w2;
        w0 = vh ? *(const short8*)(er + (size_t)eh * 192 +       q * 8) : (short8)(short)0;
        w1 = vt ? *(const short8*)(er + (size_t)et * 192 +  64 + q * 8) : (short8)(short)0;
        w2 = vh ? *(const short8*)(er + (size_t)eh * 192 + 128 + q * 8) : (short8)(short)0;

#pragma unroll
        for (int b = 0; b < 3; ++b) {
            const float* anb = (b == 0) ? an0 : ((b == 1) ? an1 : an2);
            const float* arb = (b == 0) ? ar0 : ((b == 1) ? ar1 : ar2);
            const bool val = (b == 1) ? vt : vh;
            const short8 vv = (b == 0) ? w0 : ((b == 1) ? w1 : w2);

            float pv = x * anb[l];
#pragma unroll
            for (int d = 1; d < 64; d <<= 1) pv += __shfl_xor(pv, d);

            const float4 a1 = *(const float4*)(arb + q * 8);
            const float4 a2 = *(const float4*)(arb + q * 8 + 4);
            float dd = bf2f((unsigned short)vv[0]) * a1.x
                     + bf2f((unsigned short)vv[1]) * a1.y
                     + bf2f((unsigned short)vv[2]) * a1.z
                     + bf2f((unsigned short)vv[3]) * a1.w
                     + bf2f((unsigned short)vv[4]) * a2.x
                     + bf2f((unsigned short)vv[5]) * a2.y
                     + bf2f((unsigned short)vv[6]) * a2.z
                     + bf2f((unsigned short)vv[7]) * a2.w;
            dd += __shfl_xor(dd, 1);
            dd += __shfl_xor(dd, 2);
            dd += __shfl_xor(dd, 4);

            const float lr = pv + dd;
            const float lv = lr > 0.f ? lr : 0.01f * lr;
            float mt = val ? lv : -1e30f;
            mt = fmaxf(mt, __shfl_xor(mt, 8));
            mt = fmaxf(mt, __shfl_xor(mt, 16));
            mt = fmaxf(mt, __shfl_xor(mt, 32));
            const float wg = val ? __expf(lv - mt) : 0.f;
            float s = wg;
            s += __shfl_xor(s, 8);
            s += __shfl_xor(s, 16);
            s += __shfl_xor(s, 32);

            f32x4 aA, aB;
            aA[0] = wg * bf2f((unsigned short)vv[0]);
            aA[1] = wg * bf2f((unsigned short)vv[1]);
            aA[2] = wg * bf2f((unsigned short)vv[2]);
            aA[3] = wg * bf2f((unsigned short)vv[3]);
            aB[0] = wg * bf2f((unsigned short)vv[4]);
            aB[1] = wg * bf2f((unsigned short)vv[5]);
            aB[2] = wg * bf2f((unsigned short)vv[6]);
            aB[3] = wg * bf2f((unsigned short)vv[7]);
            *(f32x4*)&sm[wv][g][q * 8] = aA;
            *(f32x4*)&sm[wv][g][q * 8 + 4] = aB;
            asm volatile("s_waitcnt lgkmcnt(0)" ::: "memory");
            __builtin_amdgcn_sched_barrier(0);
            float a = 0.f;
#pragma unroll
            for (int gg = 0; gg < 8; ++gg) a += sm[wv][gg][l];
            asm volatile("s_waitcnt lgkmcnt(0)" ::: "memory");
            __builtin_amdgcn_sched_barrier(0);

            x += fmaxf(a / (s + 1e-16f), 0.f);
        }
    } else {
#pragma unroll
        for (int b = 0; b < 3; ++b) {
            const float* anb = (b == 0) ? an0 : ((b == 1) ? an1 : an2);
            const float* arb = (b == 0) ? ar0 : ((b == 1) ? ar1 : ar2);
            const int cb = b * 64;
            const int s0 = (b == 1) ? t0 : h0, s1 = (b == 1) ? t1 : h1;

            float pv = x * anb[l];
#pragma unroll
            for (int d = 1; d < 64; d <<= 1) pv += __shfl_xor(pv, d);
            const float4 a1 = *(const float4*)(arb + q * 8);
            const float4 a2 = *(const float4*)(arb + q * 8 + 4);

            float m = -1e30f, s = 0.f;
            f32x4 aA = (f32x4)(0.f), aB = (f32x4)(0.f);
            for (int j = s0; j < s1; j += 8) {
                const int jj = j + g;
                if (jj < s1) {
                    const int e = elist[jj];
                    const short8 v = *(const short8*)(er + (size_t)e * 192 + cb + q * 8);
                    float dd = bf2f((unsigned short)v[0]) * a1.x
                             + bf2f((unsigned short)v[1]) * a1.y
                             + bf2f((unsigned short)v[2]) * a1.z
                             + bf2f((unsigned short)v[3]) * a1.w
                             + bf2f((unsigned short)v[4]) * a2.x
                             + bf2f((unsigned short)v[5]) * a2.y
                             + bf2f((unsigned short)v[6]) * a2.z
                             + bf2f((unsigned short)v[7]) * a2.w;
                    dd += __shfl_xor(dd, 1);
                    dd += __shfl_xor(dd, 2);
                    dd += __shfl_xor(dd, 4);
                    const float lg_ = pv + dd;
                    const float lv = lg_ > 0.f ? lg_ : 0.01f * lg_;
                    const float nm = fmaxf(m, lv);
                    const float rs = __expf(m - nm);
                    const float wg = __expf(lv - nm);
                    s = s * rs + wg;
                    aA[0] = aA[0] * rs + wg * bf2f((unsigned short)v[0]);
                    aA[1] = aA[1] * rs + wg * bf2f((unsigned short)v[1]);
                    aA[2] = aA[2] * rs + wg * bf2f((unsigned short)v[2]);
                    aA[3] = aA[3] * rs + wg * bf2f((unsigned short)v[3]);
                    aB[0] = aB[0] * rs + wg * bf2f((unsigned short)v[4]);
                    aB[1] = aB[1] * rs + wg * bf2f((unsigned short)v[5]);
                    aB[2] = aB[2] * rs + wg * bf2f((unsigned short)v[6]);
                    aB[3] = aB[3] * rs + wg * bf2f((unsigned short)v[7]);
                    m = nm;
                }
            }
            float mt = m;
            mt = fmaxf(mt, __shfl_xor(mt, 8));
            mt = fmaxf(mt, __shfl_xor(mt, 16));
            mt = fmaxf(mt, __shfl_xor(mt, 32));
            const float rs2 = __expf(m - mt);
            s *= rs2;
            s += __shfl_xor(s, 8);
            s += __shfl_xor(s, 16);
            s += __shfl_xor(s, 32);
#pragma unroll
            for (int c = 0; c < 4; ++c) { aA[c] *= rs2; aB[c] *= rs2; }
            *(f32x4*)&sm[wv][g][q * 8] = aA;
            *(f32x4*)&sm[wv][g][q * 8 + 4] = aB;
            asm volatile("s_waitcnt lgkmcnt(0)" ::: "memory");
            __builtin_amdgcn_sched_barrier(0);
            float a = 0.f;
#pragma unroll
            for (int gg = 0; gg < 8; ++gg) a += sm[wv][gg][l];
            asm volatile("s_waitcnt lgkmcnt(0)" ::: "memory");
            __builtin_amdgcn_sched_barrier(0);

            x += fmaxf(a / (s + 1e-16f), 0.f);
        }
    }
    out[(size_t)node * 64 + l] = x;
}

extern "C" void kernel_launch(void* const* d_in, const int* in_sizes, int n_in,
                              void* d_out, int out_size, void* d_ws, size_t ws_size,
                              hipStream_t stream)
{
    const float* xe  = (const float*)d_in[0];
    const float* xr  = (const float*)d_in[1];
    const int*   eix = (const int*)d_in[2];
    const float* Wr  = (const float*)d_in[4];
    const float* br  = (const float*)d_in[5];
    const float* Wr1 = (const float*)d_in[6];
    const float* br1 = (const float*)d_in[7];
    const float* Wr2 = (const float*)d_in[8];
    const float* br2 = (const float*)d_in[9];
    const float* ah  = (const float*)d_in[10];
    const float* ah1 = (const float*)d_in[11];
    const float* at_ = (const float*)d_in[12];
    const float* ar1 = (const float*)d_in[13];
    const float* ar2 = (const float*)d_in[14];
    const float* ar3 = (const float*)d_in[15];

    const int E = in_sizes[3];
    const int N = in_sizes[0] / 64;
    const int K = in_sizes[1] / E;
    const int M = 2 * N;
    float* out = (float*)d_out;

    char* p = (char*)d_ws;
    auto carve = [&](size_t bytes) -> void* {
        void* r = (void*)p;
        p += (bytes + 255) & ~(size_t)255;
        return r;
    };
    const int nch = (M + 255) / 256;
    unsigned short* er = (unsigned short*)carve((size_t)(E + 64) * 192 * 2);
    int* off = (int*)carve((size_t)(M + 1) * 4);
    int* elist = (int*)carve((size_t)2 * E * 4);
    int* deg = (int*)carve((size_t)M * 4);
    int* incl = (int*)carve((size_t)M * 4);
    int* cur = (int*)carve((size_t)M * 4);
    int* bsum = (int*)carve((size_t)nch * 4);
    (void)ws_size;

    const int ng = (N + 3) / 4;
    const int ntiles = (E + 63) / 64;
    const int ggrid = ntiles < 512 ? ntiles : 512;

    // cooperative CSR build (single dispatch)
    {
        const int* hh = eix;
        const int* tt = eix + E;
        int E_ = E, N_ = N;
        void* args[] = {(void*)&hh, (void*)&tt, (void*)&deg, (void*)&incl,
                        (void*)&bsum, (void*)&off, (void*)&cur, (void*)&elist,
                        (void*)&E_, (void*)&N_};
        hipLaunchCooperativeKernel((void*)csr_coop_k, dim3(1024), dim3(256),
                                   args, 0, stream);
    }

    gemm_k<<<ggrid, 512, 0, stream>>>(xr, Wr, Wr1, Wr2, br, br1, br2,
                                      er, E, ntiles, K);

    gat3_k<<<ng, 256, 0, stream>>>(off, elist, er, xe, out,
                                   ah, at_, ah1, ar1, ar2, ar3, N);
}

// Round 22
// 356.076 us; speedup vs baseline: 2.2914x; 2.2914x over previous
//
#include <hip/hip_runtime.h>
#include <hip/hip_bf16.h>

typedef __attribute__((ext_vector_type(8))) short short8;
typedef __attribute__((ext_vector_type(4))) float f32x4;

#define DEV __device__ __forceinline__

// LDS-only barrier: drains LDS ops, leaves global loads (vmcnt) in flight.
#define BARRIER() do { asm volatile("s_waitcnt lgkmcnt(0)" ::: "memory"); \
                       __builtin_amdgcn_s_barrier(); \
                       __builtin_amdgcn_sched_barrier(0); } while (0)

DEV unsigned short f2bf(float f) {
    unsigned u = __float_as_uint(f);
    u += 0x7FFFu + ((u >> 16) & 1u);
    return (unsigned short)(u >> 16);
}
DEV float bf2f(unsigned short h) { return __uint_as_float(((unsigned)h) << 16); }
DEV unsigned pk2(float lo, float hi) {
    float2 f; f.x = lo; f.y = hi;
    __hip_bfloat162 h = __float22bfloat162_rn(f);
    unsigned r; __builtin_memcpy(&r, &h, 4);
    return r;
}
union S8 { short8 s; unsigned u[4]; };

// ---------------------------------------------------------------------------
// bf16 MFMA GEMM: 64-edge x 192-out tile, 512 threads (8 waves).
// Wave w: col-group c=w&3 (col-tiles [3c,3c+3)), row half rh=w>>2.
// W staged once per block DIRECTLY FROM f32 inputs (inline cvt; no wconv
// kernel, no wbf buffer) -> W fragments hoisted to registers; then
// double-buffered As (2 x 24.6 KB in the same 73.7 KB region) -> ONE
// lgkm barrier per tile. Epilogue = bias + direct packed er store.
//   er[e][0:192] = x_r[e] @ [W0;W1;W2]^T + b   (bf16)
// ---------------------------------------------------------------------------
__global__ __launch_bounds__(512, 2) void gemm_k(
    const float* __restrict__ xr,
    const float* __restrict__ W0, const float* __restrict__ W1, const float* __restrict__ W2,
    const float* __restrict__ b0, const float* __restrict__ b1, const float* __restrict__ b2,
    unsigned short* __restrict__ er,
    int E, int ntiles, int K)
{
    __shared__ __align__(16) unsigned short ShBuf[192 * 192];  // 73.7 KB, overlaid
    unsigned short* Ws = ShBuf;                      // phase 1
    const int t = threadIdx.x;
    const int w = t >> 6, l = t & 63, l15 = l & 15, lg = l >> 4;
    const int cgrp = w & 3, rh = w >> 2;       // col-group, row-half
    const int srow = t >> 3, sq = t & 7;       // staging: 64 rows x 8 thr/row x 24 f32

    // ---- stage W into LDS once, f32 -> bf16 inline: 4608 chunks of 16B ----
#pragma unroll
    for (int j = 0; j < 9; ++j) {
        const int c = j * 512 + t;
        const int gc = c / 24, pos = c - gc * 24;
        const int m = gc >> 6, row = gc & 63;
        const float* Wm = (m == 0) ? W0 : ((m == 1) ? W1 : W2);
        const float4 u0 = *(const float4*)(Wm + row * 192 + pos * 8);
        const float4 u1 = *(const float4*)(Wm + row * 192 + pos * 8 + 4);
        S8 o;
        o.u[0] = pk2(u0.x, u0.y); o.u[1] = pk2(u0.z, u0.w);
        o.u[2] = pk2(u1.x, u1.y); o.u[3] = pk2(u1.z, u1.w);
        const unsigned byte = (unsigned)(gc * 384 + pos * 16);
        *(short8*)((char*)Ws + (byte ^ ((gc & 7) << 4))) = o.s;
    }

    const int G = gridDim.x;
    float4 nv[6];
    // prologue: prefetch tile 0's A slice (in flight during W staging/hoist)
    if (blockIdx.x < ntiles) {
        const long e = (long)blockIdx.x * 64 + srow;
        const bool ok = e < E;
        const float* sp = xr + e * (long)K + sq * 24;
#pragma unroll
        for (int r = 0; r < 6; ++r)
            nv[r] = ok ? *(const float4*)(sp + r * 4) : make_float4(0.f, 0.f, 0.f, 0.f);
    }

    BARRIER();  // Ws visible
    // ---- hoist W fragments to registers (LDS region will be overwritten) ----
    short8 bfr[3][6];
#pragma unroll
    for (int i = 0; i < 3; ++i) {
        const int gc = (cgrp * 3 + i) * 16 + l15;
#pragma unroll
        for (int ks = 0; ks < 6; ++ks) {
            const unsigned byte = (unsigned)(gc * 384 + ks * 64 + lg * 16);
            bfr[i][ks] = *(const short8*)((const char*)Ws + (byte ^ ((gc & 7) << 4)));
        }
    }
    BARRIER();  // all bfr reads done -> region reusable for As buffers

    int p = 0;
    for (int tile = blockIdx.x; tile < ntiles; tile += G, p ^= 1) {
        const long e0 = (long)tile * 64;
        char* Ab = (char*)(ShBuf + p * 64 * 192);
        // ---- convert prefetched regs -> bf16 -> swizzled LDS (buf p) ----
        {
            const unsigned swz = (unsigned)((srow & 7) << 4);
            S8 o0, o1, o2;
            o0.u[0] = pk2(nv[0].x, nv[0].y); o0.u[1] = pk2(nv[0].z, nv[0].w);
            o0.u[2] = pk2(nv[1].x, nv[1].y); o0.u[3] = pk2(nv[1].z, nv[1].w);
            o1.u[0] = pk2(nv[2].x, nv[2].y); o1.u[1] = pk2(nv[2].z, nv[2].w);
            o1.u[2] = pk2(nv[3].x, nv[3].y); o1.u[3] = pk2(nv[3].z, nv[3].w);
            o2.u[0] = pk2(nv[4].x, nv[4].y); o2.u[1] = pk2(nv[4].z, nv[4].w);
            o2.u[2] = pk2(nv[5].x, nv[5].y); o2.u[3] = pk2(nv[5].z, nv[5].w);
            const unsigned byte0 = (unsigned)(srow * 384 + sq * 48);
            *(short8*)(Ab + ((byte0 +  0) ^ swz)) = o0.s;
            *(short8*)(Ab + ((byte0 + 16) ^ swz)) = o1.s;
            *(short8*)(Ab + ((byte0 + 32) ^ swz)) = o2.s;
        }
        // ---- issue next tile's loads (stay in flight through MFMA) ----
        {
            const int nxt = tile + G;
            if (nxt < ntiles) {
                const long e = (long)nxt * 64 + srow;
                const bool ok = e < E;
                const float* sp = xr + e * (long)K + sq * 24;
#pragma unroll
                for (int r = 0; r < 6; ++r)
                    nv[r] = ok ? *(const float4*)(sp + r * 4)
                               : make_float4(0.f, 0.f, 0.f, 0.f);
            }
        }
        BARRIER();  // buf p staging visible (single barrier per tile)
        // ---- MFMA (swapped: D col=edge, row=feature); W from registers ----
        f32x4 acc[2][3];
#pragma unroll
        for (int rt = 0; rt < 2; ++rt)
#pragma unroll
            for (int i = 0; i < 3; ++i) acc[rt][i] = (f32x4)(0.f);
#pragma unroll
        for (int ks = 0; ks < 6; ++ks) {
            short8 af[2];
#pragma unroll
            for (int rt = 0; rt < 2; ++rt) {
                const int row = rh * 32 + rt * 16 + l15;
                const unsigned byte = (unsigned)(row * 384 + ks * 64 + lg * 16);
                af[rt] = *(const short8*)((const char*)Ab + (byte ^ ((row & 7) << 4)));
            }
#pragma unroll
            for (int i = 0; i < 3; ++i)
#pragma unroll
                for (int rt = 0; rt < 2; ++rt)
                    acc[rt][i] = __builtin_amdgcn_mfma_f32_16x16x32_bf16(bfr[i][ks], af[rt], acc[rt][i], 0, 0, 0);
        }
        // ---- epilogue: bias + direct packed er store (no LDS) ----
#pragma unroll
        for (int i = 0; i < 3; ++i) {
            const int ct = cgrp * 3 + i, m = ct >> 2;
            const int cb_ = ((ct & 3) << 4) + (lg << 2);
            const float* bp = (m == 0) ? b0 : ((m == 1) ? b1 : b2);
            const float4 bb = *(const float4*)(bp + cb_);
            const int fb = ct * 16 + (lg << 2);
#pragma unroll
            for (int rt = 0; rt < 2; ++rt) {
                const int edge = rh * 32 + rt * 16 + l15;
                const long ee = e0 + edge;
                if (ee < E) {
                    uint2 pkv;
                    pkv.x = pk2(acc[rt][i][0] + bb.x, acc[rt][i][1] + bb.y);
                    pkv.y = pk2(acc[rt][i][2] + bb.z, acc[rt][i][3] + bb.w);
                    *(uint2*)(er + (size_t)ee * 192 + fb) = pkv;
                }
            }
        }
    }
}

// ---------------------------------------------------------------------------
// Fused CSR build over 2N segments: h-graph at [0,N), t-graph at [N,2N)
// (discrete kernels -- cooperative version was a 10x regression, r21)
// ---------------------------------------------------------------------------
__global__ __launch_bounds__(256) void count2_k(const int* __restrict__ h,
                                                const int* __restrict__ tt,
                                                int* __restrict__ deg, int E, int N)
{
    const int e = blockIdx.x * 256 + threadIdx.x;
    if (e >= E) return;
    atomicAdd(&deg[h[e]], 1);
    atomicAdd(&deg[N + tt[e]], 1);
}

__global__ __launch_bounds__(256) void scan1_k(const int* __restrict__ deg,
                                               int* __restrict__ incl,
                                               int* __restrict__ bsum, int M)
{
    __shared__ int buf[256];
    const int tid = threadIdx.x;
    const int n = blockIdx.x * 256 + tid;
    buf[tid] = (n < M) ? deg[n] : 0;
    __syncthreads();
    for (int d = 1; d < 256; d <<= 1) {
        int v = (tid >= d) ? buf[tid - d] : 0;
        __syncthreads();
        buf[tid] += v;
        __syncthreads();
    }
    if (n < M) incl[n] = buf[tid];
    if (tid == 255) bsum[blockIdx.x] = buf[255];
}

// wave-shuffle scan over block sums (single block)
__global__ __launch_bounds__(256) void scan2_k(int* __restrict__ bsum, int nb)
{
    __shared__ int wsum[4];
    const int tid = threadIdx.x, l = tid & 63, wv = tid >> 6;
    int base = 0;
    for (int start = 0; start < nb; start += 1024) {
        const int i0 = start + tid * 4;
        int v0 = 0, v1 = 0, v2 = 0, v3 = 0;
        if (i0 < nb)     v0 = bsum[i0];
        if (i0 + 1 < nb) v1 = bsum[i0 + 1];
        if (i0 + 2 < nb) v2 = bsum[i0 + 2];
        if (i0 + 3 < nb) v3 = bsum[i0 + 3];
        const int tsum = v0 + v1 + v2 + v3;
        int sc = tsum;
#pragma unroll
        for (int d = 1; d < 64; d <<= 1) {
            const int o = __shfl_up(sc, d);
            if (l >= d) sc += o;
        }
        if (l == 63) wsum[wv] = sc;
        __syncthreads();
        int woff = base;
        for (int q = 0; q < wv; ++q) woff += wsum[q];
        int run = woff + sc - tsum;
        run += v0; if (i0 < nb)     bsum[i0] = run;
        run += v1; if (i0 + 1 < nb) bsum[i0 + 1] = run;
        run += v2; if (i0 + 2 < nb) bsum[i0 + 2] = run;
        run += v3; if (i0 + 3 < nb) bsum[i0 + 3] = run;
        base += wsum[0] + wsum[1] + wsum[2] + wsum[3];
        __syncthreads();
    }
}

__global__ __launch_bounds__(256) void off_k(const int* __restrict__ deg,
                                             const int* __restrict__ incl,
                                             const int* __restrict__ bsum,
                                             int* __restrict__ off,
                                             int* __restrict__ cur, int M, int tot)
{
    const int n = blockIdx.x * 256 + threadIdx.x;
    if (n < M) {
        const int prev = (blockIdx.x > 0) ? bsum[blockIdx.x - 1] : 0;
        const int o = prev + incl[n] - deg[n];
        off[n] = o;
        cur[n] = o;
    }
    if (n == 0) off[M] = tot;
}

__global__ __launch_bounds__(256) void fill2_k(const int* __restrict__ h,
                                               const int* __restrict__ tt,
                                               int* __restrict__ cur,
                                               int* __restrict__ elist, int E, int N)
{
    const int e = blockIdx.x * 256 + threadIdx.x;
    if (e >= E) return;
    const int p = atomicAdd(&cur[h[e]], 1);
    elist[p] = e;
    const int p2 = atomicAdd(&cur[N + tt[e]], 1);
    elist[p2] = e;
}

// ---------------------------------------------------------------------------
// Fully fused 3-block GAT: wave per node, x in registers across blocks.
// ed (= er.ar) computed IN-REGISTER from the er slice; fast path (deg<=8
// both lists): one gather round for all three blocks. Slow path: online
// softmax loop.  (round-20, unchanged)
// ---------------------------------------------------------------------------
__global__ __launch_bounds__(256, 6) void gat3_k(
    const int* __restrict__ off, const int* __restrict__ elist,
    const unsigned short* __restrict__ er,
    const float* __restrict__ xe, float* __restrict__ out,
    const float* __restrict__ an0, const float* __restrict__ an1,
    const float* __restrict__ an2,
    const float* __restrict__ ar0, const float* __restrict__ ar1,
    const float* __restrict__ ar2, int N)
{
    __shared__ float sm[4][8][64];
    const int wv = threadIdx.x >> 6;
    const int node = blockIdx.x * 4 + wv;
    if (node >= N) return;
    const int l = threadIdx.x & 63;
    const int g = l >> 3, q = l & 7;

    const int h0 = off[node], h1 = off[node + 1];
    const int t0 = off[N + node], t1 = off[N + node + 1];
    float x = xe[(size_t)node * 64 + l];

    if ((h1 - h0) <= 8 && (t1 - t0) <= 8) {
        const bool vh = g < (h1 - h0), vt = g < (t1 - t0);
        const int eh = vh ? elist[h0 + g] : 0;
        const int et = vt ? elist[t0 + g] : 0;
        short8 w0, w1, w2;
        w0 = vh ? *(const short8*)(er + (size_t)eh * 192 +       q * 8) : (short8)(short)0;
        w1 = vt ? *(const short8*)(er + (size_t)et * 192 +  64 + q * 8) : (short8)(short)0;
        w2 = vh ? *(const short8*)(er + (size_t)eh * 192 + 128 + q * 8) : (short8)(short)0;

#pragma unroll
        for (int b = 0; b < 3; ++b) {
            const float* anb = (b == 0) ? an0 : ((b == 1) ? an1 : an2);
            const float* arb = (b == 0) ? ar0 : ((b == 1) ? ar1 : ar2);
            const bool val = (b == 1) ? vt : vh;
            const short8 vv = (b == 0) ? w0 : ((b == 1) ? w1 : w2);

            float pv = x * anb[l];
#pragma unroll
            for (int d = 1; d < 64; d <<= 1) pv += __shfl_xor(pv, d);

            const float4 a1 = *(const float4*)(arb + q * 8);
            const float4 a2 = *(const float4*)(arb + q * 8 + 4);
            float dd = bf2f((unsigned short)vv[0]) * a1.x
                     + bf2f((unsigned short)vv[1]) * a1.y
                     + bf2f((unsigned short)vv[2]) * a1.z
                     + bf2f((unsigned short)vv[3]) * a1.w
                     + bf2f((unsigned short)vv[4]) * a2.x
                     + bf2f((unsigned short)vv[5]) * a2.y
                     + bf2f((unsigned short)vv[6]) * a2.z
                     + bf2f((unsigned short)vv[7]) * a2.w;
            dd += __shfl_xor(dd, 1);
            dd += __shfl_xor(dd, 2);
            dd += __shfl_xor(dd, 4);

            const float lr = pv + dd;
            const float lv = lr > 0.f ? lr : 0.01f * lr;
            float mt = val ? lv : -1e30f;
            mt = fmaxf(mt, __shfl_xor(mt, 8));
            mt = fmaxf(mt, __shfl_xor(mt, 16));
            mt = fmaxf(mt, __shfl_xor(mt, 32));
            const float wg = val ? __expf(lv - mt) : 0.f;
            float s = wg;
            s += __shfl_xor(s, 8);
            s += __shfl_xor(s, 16);
            s += __shfl_xor(s, 32);

            f32x4 aA, aB;
            aA[0] = wg * bf2f((unsigned short)vv[0]);
            aA[1] = wg * bf2f((unsigned short)vv[1]);
            aA[2] = wg * bf2f((unsigned short)vv[2]);
            aA[3] = wg * bf2f((unsigned short)vv[3]);
            aB[0] = wg * bf2f((unsigned short)vv[4]);
            aB[1] = wg * bf2f((unsigned short)vv[5]);
            aB[2] = wg * bf2f((unsigned short)vv[6]);
            aB[3] = wg * bf2f((unsigned short)vv[7]);
            *(f32x4*)&sm[wv][g][q * 8] = aA;
            *(f32x4*)&sm[wv][g][q * 8 + 4] = aB;
            asm volatile("s_waitcnt lgkmcnt(0)" ::: "memory");
            __builtin_amdgcn_sched_barrier(0);
            float a = 0.f;
#pragma unroll
            for (int gg = 0; gg < 8; ++gg) a += sm[wv][gg][l];
            asm volatile("s_waitcnt lgkmcnt(0)" ::: "memory");
            __builtin_amdgcn_sched_barrier(0);

            x += fmaxf(a / (s + 1e-16f), 0.f);
        }
    } else {
#pragma unroll
        for (int b = 0; b < 3; ++b) {
            const float* anb = (b == 0) ? an0 : ((b == 1) ? an1 : an2);
            const float* arb = (b == 0) ? ar0 : ((b == 1) ? ar1 : ar2);
            const int cb = b * 64;
            const int s0 = (b == 1) ? t0 : h0, s1 = (b == 1) ? t1 : h1;

            float pv = x * anb[l];
#pragma unroll
            for (int d = 1; d < 64; d <<= 1) pv += __shfl_xor(pv, d);
            const float4 a1 = *(const float4*)(arb + q * 8);
            const float4 a2 = *(const float4*)(arb + q * 8 + 4);

            float m = -1e30f, s = 0.f;
            f32x4 aA = (f32x4)(0.f), aB = (f32x4)(0.f);
            for (int j = s0; j < s1; j += 8) {
                const int jj = j + g;
                if (jj < s1) {
                    const int e = elist[jj];
                    const short8 v = *(const short8*)(er + (size_t)e * 192 + cb + q * 8);
                    float dd = bf2f((unsigned short)v[0]) * a1.x
                             + bf2f((unsigned short)v[1]) * a1.y
                             + bf2f((unsigned short)v[2]) * a1.z
                             + bf2f((unsigned short)v[3]) * a1.w
                             + bf2f((unsigned short)v[4]) * a2.x
                             + bf2f((unsigned short)v[5]) * a2.y
                             + bf2f((unsigned short)v[6]) * a2.z
                             + bf2f((unsigned short)v[7]) * a2.w;
                    dd += __shfl_xor(dd, 1);
                    dd += __shfl_xor(dd, 2);
                    dd += __shfl_xor(dd, 4);
                    const float lg_ = pv + dd;
                    const float lv = lg_ > 0.f ? lg_ : 0.01f * lg_;
                    const float nm = fmaxf(m, lv);
                    const float rs = __expf(m - nm);
                    const float wg = __expf(lv - nm);
                    s = s * rs + wg;
                    aA[0] = aA[0] * rs + wg * bf2f((unsigned short)v[0]);
                    aA[1] = aA[1] * rs + wg * bf2f((unsigned short)v[1]);
                    aA[2] = aA[2] * rs + wg * bf2f((unsigned short)v[2]);
                    aA[3] = aA[3] * rs + wg * bf2f((unsigned short)v[3]);
                    aB[0] = aB[0] * rs + wg * bf2f((unsigned short)v[4]);
                    aB[1] = aB[1] * rs + wg * bf2f((unsigned short)v[5]);
                    aB[2] = aB[2] * rs + wg * bf2f((unsigned short)v[6]);
                    aB[3] = aB[3] * rs + wg * bf2f((unsigned short)v[7]);
                    m = nm;
                }
            }
            float mt = m;
            mt = fmaxf(mt, __shfl_xor(mt, 8));
            mt = fmaxf(mt, __shfl_xor(mt, 16));
            mt = fmaxf(mt, __shfl_xor(mt, 32));
            const float rs2 = __expf(m - mt);
            s *= rs2;
            s += __shfl_xor(s, 8);
            s += __shfl_xor(s, 16);
            s += __shfl_xor(s, 32);
#pragma unroll
            for (int c = 0; c < 4; ++c) { aA[c] *= rs2; aB[c] *= rs2; }
            *(f32x4*)&sm[wv][g][q * 8] = aA;
            *(f32x4*)&sm[wv][g][q * 8 + 4] = aB;
            asm volatile("s_waitcnt lgkmcnt(0)" ::: "memory");
            __builtin_amdgcn_sched_barrier(0);
            float a = 0.f;
#pragma unroll
            for (int gg = 0; gg < 8; ++gg) a += sm[wv][gg][l];
            asm volatile("s_waitcnt lgkmcnt(0)" ::: "memory");
            __builtin_amdgcn_sched_barrier(0);

            x += fmaxf(a / (s + 1e-16f), 0.f);
        }
    }
    out[(size_t)node * 64 + l] = x;
}

extern "C" void kernel_launch(void* const* d_in, const int* in_sizes, int n_in,
                              void* d_out, int out_size, void* d_ws, size_t ws_size,
                              hipStream_t stream)
{
    const float* xe  = (const float*)d_in[0];
    const float* xr  = (const float*)d_in[1];
    const int*   eix = (const int*)d_in[2];
    const float* Wr  = (const float*)d_in[4];
    const float* br  = (const float*)d_in[5];
    const float* Wr1 = (const float*)d_in[6];
    const float* br1 = (const float*)d_in[7];
    const float* Wr2 = (const float*)d_in[8];
    const float* br2 = (const float*)d_in[9];
    const float* ah  = (const float*)d_in[10];
    const float* ah1 = (const float*)d_in[11];
    const float* at_ = (const float*)d_in[12];
    const float* ar1 = (const float*)d_in[13];
    const float* ar2 = (const float*)d_in[14];
    const float* ar3 = (const float*)d_in[15];

    const int E = in_sizes[3];
    const int N = in_sizes[0] / 64;
    const int K = in_sizes[1] / E;
    const int M = 2 * N;
    float* out = (float*)d_out;

    char* p = (char*)d_ws;
    auto carve = [&](size_t bytes) -> void* {
        void* r = (void*)p;
        p += (bytes + 255) & ~(size_t)255;
        return r;
    };
    const int nb = (M + 255) / 256;
    unsigned short* er = (unsigned short*)carve((size_t)(E + 64) * 192 * 2);
    int* off = (int*)carve((size_t)(M + 1) * 4);
    int* elist = (int*)carve((size_t)2 * E * 4);
    int* deg = (int*)carve((size_t)M * 4);
    int* incl = (int*)carve((size_t)M * 4);
    int* cur = (int*)carve((size_t)M * 4);
    int* bsum = (int*)carve((size_t)nb * 4);
    (void)ws_size;

    const int Eg = (E + 255) / 256;
    const int ng = (N + 3) / 4;
    const int ntiles = (E + 63) / 64;
    const int ggrid = ntiles < 512 ? ntiles : 512;

    hipMemsetAsync(deg, 0, (size_t)M * 4, stream);
    count2_k<<<Eg, 256, 0, stream>>>(eix, eix + E, deg, E, N);
    scan1_k<<<nb, 256, 0, stream>>>(deg, incl, bsum, M);
    scan2_k<<<1, 256, 0, stream>>>(bsum, nb);
    off_k<<<nb, 256, 0, stream>>>(deg, incl, bsum, off, cur, M, 2 * E);
    fill2_k<<<Eg, 256, 0, stream>>>(eix, eix + E, cur, elist, E, N);

    gemm_k<<<ggrid, 512, 0, stream>>>(xr, Wr, Wr1, Wr2, br, br1, br2,
                                      er, E, ntiles, K);

    gat3_k<<<ng, 256, 0, stream>>>(off, elist, er, xe, out,
                                   ah, at_, ah1, ar1, ar2, ar3, N);
}